// Round 13
// baseline (368.517 us; speedup 1.0000x reference)
//
#include <hip/hip_runtime.h>
#include <hip/hip_bf16.h>

typedef __attribute__((ext_vector_type(4))) float f32x4;
typedef __attribute__((ext_vector_type(16))) float f32x16;
typedef __attribute__((ext_vector_type(8))) short bf16x8;

#define GBL_AS(p) (const __attribute__((address_space(1))) void*)(p)
#define LDS_AS(p) (__attribute__((address_space(3))) void*)(p)

__device__ __forceinline__ void gload_lds16(const void* g, void* l) {
  __builtin_amdgcn_global_load_lds(GBL_AS(g), LDS_AS(l), 16, 0, 0);
}

__device__ __forceinline__ ushort f2bf(float f) {
  union { float f; unsigned int u; } v; v.f = f;
  unsigned int r = v.u + 0x7fffu + ((v.u >> 16) & 1u);
  return (ushort)(r >> 16);
}

// ---------------------------------------------------------------- fused prep:
// blocks [0,8192): cast x f32->bf16 (float4/ushort4 chunks)
// blocks [8192,11264): transpose+cast w_qkv [2048][6144] -> [6144][2048] bf16
__global__ void prep_kernel(const float4* __restrict__ x4,
                            ushort4* __restrict__ xb4,
                            const float* __restrict__ wqkv,
                            ushort* __restrict__ wqkvt) {
  __shared__ float tile[64][65];
  const int blk = blockIdx.x;
  if (blk < 8192) {
    int i = blk * 256 + threadIdx.x;
    float4 v = x4[i];
    ushort4 o;
    o.x = f2bf(v.x); o.y = f2bf(v.y); o.z = f2bf(v.z); o.w = f2bf(v.w);
    xb4[i] = o;
  } else {
    const int idx = blk - 8192;
    const int bx = idx % 96, by = idx / 96;   // 96 x 32 tiles
    const int C = 6144, R = 2048;
    int tx = threadIdx.x & 63, ty = threadIdx.x >> 6;
    int r0 = by * 64, c0 = bx * 64;
#pragma unroll
    for (int i = 0; i < 64; i += 4)
      tile[ty + i][tx] = wqkv[(size_t)(r0 + ty + i) * C + (c0 + tx)];
    __syncthreads();
#pragma unroll
    for (int i = 0; i < 64; i += 4)
      wqkvt[(size_t)(c0 + ty + i) * R + (r0 + tx)] = f2bf(tile[tx][ty + i]);
  }
}

// ------------------------------------------------- transpose + cast: [R][C]f32 -> [C][R]bf16
__global__ void transpose_cast_kernel(const float* __restrict__ in,
                                      ushort* __restrict__ out, int R, int C) {
  __shared__ float tile[64][65];
  int tx = threadIdx.x & 63, ty = threadIdx.x >> 6;
  int r0 = blockIdx.y * 64, c0 = blockIdx.x * 64;
#pragma unroll
  for (int i = 0; i < 64; i += 4)
    tile[ty + i][tx] = in[(size_t)(r0 + ty + i) * C + (c0 + tx)];
  __syncthreads();
#pragma unroll
  for (int i = 0; i < 64; i += 4)
    out[(size_t)(c0 + ty + i) * R + (r0 + tx)] = f2bf(tile[tx][ty + i]);
}

// ---------------------------------------------------------------- bf16 GEMM, Bt layout
// A: [M][K] bf16, Bt: [N][K] bf16.  MODE 0: C=f32 [M][N] + bias.
// MODE 1: QKV scatter: Q scaled by log2(e)/sqrt(128) -> [B*H][S][D];
//         K -> [B*H][S][D]; V -> transposed [B*H][D][S].
template <int MODE>
__global__ __launch_bounds__(256, 2) void gemm_bt_kernel(
    const ushort* __restrict__ A, const ushort* __restrict__ Bt,
    const float* __restrict__ bias, float* __restrict__ C,
    ushort* __restrict__ Qo, ushort* __restrict__ Ko, ushort* __restrict__ Vo,
    int M, int N, int K) {
  __shared__ ushort As[128 * 64];
  __shared__ ushort Bs[128 * 64];
  const int tid = threadIdx.x;
  const int w = tid >> 6, l = tid & 63;
  const int wr = w >> 1, wc = w & 1;
  const int m0 = blockIdx.y * 128, n0 = blockIdx.x * 128;

  f32x4 acc[4][4] = {};

  const int lr = l >> 3;             // row-in-1KB-group (0..7)
  const int lc = (l & 7) ^ lr;       // pre-swizzled source chunk

  for (int k0 = 0; k0 < K; k0 += 64) {
#pragma unroll
    for (int i = 0; i < 4; ++i) {
      int row = i * 32 + w * 8 + lr;
      gload_lds16(A + (size_t)(m0 + row) * K + k0 + lc * 8,
                  (char*)As + (i * 32 + w * 8) * 128);
      gload_lds16(Bt + (size_t)(n0 + row) * K + k0 + lc * 8,
                  (char*)Bs + (i * 32 + w * 8) * 128);
    }
    __syncthreads();
    const char* Ab = (const char*)As;
    const char* Bb = (const char*)Bs;
#pragma unroll
    for (int ks = 0; ks < 2; ++ks) {
      bf16x8 af[4], bfr[4];
      int cc = ks * 4 + (l >> 4);
#pragma unroll
      for (int mi = 0; mi < 4; ++mi) {
        int row = wr * 64 + mi * 16 + (l & 15);
        af[mi] = *(const bf16x8*)(Ab + row * 128 + ((cc ^ (row & 7)) << 4));
      }
#pragma unroll
      for (int ni = 0; ni < 4; ++ni) {
        int row = wc * 64 + ni * 16 + (l & 15);
        bfr[ni] = *(const bf16x8*)(Bb + row * 128 + ((cc ^ (row & 7)) << 4));
      }
#pragma unroll
      for (int mi = 0; mi < 4; ++mi)
#pragma unroll
        for (int ni = 0; ni < 4; ++ni)
          acc[mi][ni] = __builtin_amdgcn_mfma_f32_16x16x32_bf16(
              af[mi], bfr[ni], acc[mi][ni], 0, 0, 0);
    }
    __syncthreads();
  }

  if (MODE == 0) {
#pragma unroll
    for (int mi = 0; mi < 4; ++mi) {
      int row = m0 + wr * 64 + mi * 16 + ((l >> 4) << 2);
#pragma unroll
      for (int ni = 0; ni < 4; ++ni) {
        int col = n0 + wc * 64 + ni * 16 + (l & 15);
        float b = bias[col];
#pragma unroll
        for (int r = 0; r < 4; ++r)
          C[(size_t)(row + r) * N + col] = acc[mi][ni][r] + b;
      }
    }
  } else {
    // log2(e)/sqrt(128): softmax runs in exp2 domain
    const float qscale = 0.08838834764831845f * 1.4426950408889634f;
#pragma unroll
    for (int ni = 0; ni < 4; ++ni) {
      int n = n0 + wc * 64 + ni * 16 + (l & 15);
      int which = n >> 11;
      int cc2 = n & 2047;
      int h = cc2 >> 7, d = cc2 & 127;
      float b = bias[n];
#pragma unroll
      for (int mi = 0; mi < 4; ++mi) {
        int m = m0 + wr * 64 + mi * 16 + ((l >> 4) << 2);
        int bb = m >> 11, s = m & 2047;
        int bh = bb * 16 + h;
        if (which == 0) {
#pragma unroll
          for (int r = 0; r < 4; ++r)
            Qo[((size_t)bh * 2048 + s + r) * 128 + d] =
                f2bf((acc[mi][ni][r] + b) * qscale);
        } else if (which == 1) {
#pragma unroll
          for (int r = 0; r < 4; ++r)
            Ko[((size_t)bh * 2048 + s + r) * 128 + d] = f2bf(acc[mi][ni][r] + b);
        } else {
          ushort4 pk;
          pk.x = f2bf(acc[mi][ni][0] + b);
          pk.y = f2bf(acc[mi][ni][1] + b);
          pk.z = f2bf(acc[mi][ni][2] + b);
          pk.w = f2bf(acc[mi][ni][3] + b);
          *(ushort4*)(Vo + ((size_t)bh * 128 + d) * 2048 + s) = pk;
        }
      }
    }
  }
}

// ---------------------------------------------------------------- flash attention
// THIS ROUND: 4 waves x 64 q-rows (2 strips of 32) — halves LDS-read
// amplification (kf/vf fragments are wave-invariant; each read now feeds
// 2 strips' MFMAs). KVBLK=128, K/V dbuf 128KB, 1 block/CU, 1 wave/SIMD
// (launch_bounds(256,1): VGPR ~410, under 450 no-spill line).
// Swapped-QK^T; per-strip in-register softmax (exp2, defer-max);
// cvt_pk+permlane P->bf16. Waves 0-1: heavy qb=8+j; waves 2-3: light 7-j.
__global__ __launch_bounds__(256, 1) void attn_kernel(
    const ushort* __restrict__ Qg, const ushort* __restrict__ Kg,
    const ushort* __restrict__ Vtg, ushort* __restrict__ Og) {
  constexpr int S = 2048, D = 128;
  __shared__ ushort Kl[2][128 * 128];
  __shared__ ushort Vl[2][128 * 128];

  const int tid = threadIdx.x, w = tid >> 6, l = tid & 63;
  const int lid = blockIdx.x;
  const int bh = lid & 31;            // same-bh blocks share an XCD
  const int j = lid >> 5;             // pair index 0..7
  const int g = w >> 1, wv = w & 1;
  const int qb = (g == 0) ? (8 + j) : (7 - j);
  const int wq0 = qb * 128 + wv * 64; // wave owns rows [wq0, wq0+64)
  const int nt_blk = 9 + j;
  const int ql = l & 31, h32 = l >> 5;

  const ushort* Qb = Qg + (size_t)bh * S * D;
  const ushort* Kb = Kg + (size_t)bh * S * D;
  const ushort* Vb = Vtg + (size_t)bh * D * S;

  bf16x8 qf[2][8];
#pragma unroll
  for (int r = 0; r < 2; ++r)
#pragma unroll
    for (int ks = 0; ks < 8; ++ks)
      qf[r][ks] = *(const bf16x8*)(Qb + (size_t)(wq0 + r * 32 + ql) * D +
                                   ks * 16 + h32 * 8);

  f32x16 o[2][4];
#pragma unroll
  for (int r = 0; r < 2; ++r)
#pragma unroll
    for (int dt = 0; dt < 4; ++dt) o[r][dt] = 0.f;
  float mrun[2] = {-1e30f, -1e30f}, lrun[2] = {0.f, 0.f};

  // stage one 128-kv tile: per wave 8 K-groups + 8 V-groups of 1KB
  auto stage = [&](int t, int buf) {
    const int k0 = t * 128;
#pragma unroll
    for (int s2 = 0; s2 < 8; ++s2) {
      int i = w * 8 + s2;
      int row = i * 4 + (l >> 4);
      int ck = (l & 15) ^ (row & 7);
      gload_lds16(Kb + (size_t)(k0 + row) * D + ck * 8,
                  (char*)Kl[buf] + i * 1024);
    }
#pragma unroll
    for (int s2 = 0; s2 < 8; ++s2) {
      int i = w * 8 + s2;
      int row = i * 4 + (l >> 4);
      int ck = (l & 15) ^ (row & 7);
      gload_lds16(Vb + (size_t)row * S + k0 + ck * 8,
                  (char*)Vl[buf] + i * 1024);
    }
  };

  stage(0, 0);

  for (int t = 0; t < nt_blk; ++t) {
    const int cur = t & 1;
    const int k0 = t * 128;
    if (t + 1 < nt_blk) {
      stage(t + 1, cur ^ 1);
      asm volatile("s_waitcnt vmcnt(16)" ::: "memory");
    } else {
      asm volatile("s_waitcnt vmcnt(0)" ::: "memory");
    }
    __builtin_amdgcn_s_barrier();

    if (k0 < wq0 + 64) {                 // wave covers rows wq0..wq0+63
      const char* Kc = (const char*)Kl[cur];
      const char* Vc = (const char*)Vl[cur];
      const int swz0 = ql & 7;

      // ---- QK^T: kf fragments shared by both q-strips
      f32x16 sa[2][4];
#pragma unroll
      for (int r = 0; r < 2; ++r)
#pragma unroll
        for (int kt = 0; kt < 4; ++kt) sa[r][kt] = 0.f;
#pragma unroll
      for (int p = 0; p < 2; ++p) {
        bf16x8 kf0[8], kf1[8];
        const char* base0 = Kc + (p * 64 + ql) * 256;
        const char* base1 = Kc + (p * 64 + 32 + ql) * 256;
#pragma unroll
        for (int ks = 0; ks < 8; ++ks) {
          int c = 2 * ks + h32;
          kf0[ks] = *(const bf16x8*)(base0 + ((c ^ swz0) << 4));
          kf1[ks] = *(const bf16x8*)(base1 + ((c ^ swz0) << 4));
        }
        __builtin_amdgcn_s_setprio(1);
#pragma unroll
        for (int ks = 0; ks < 8; ++ks) {
          sa[0][p * 2] = __builtin_amdgcn_mfma_f32_32x32x16_bf16(
              kf0[ks], qf[0][ks], sa[0][p * 2], 0, 0, 0);
          sa[1][p * 2] = __builtin_amdgcn_mfma_f32_32x32x16_bf16(
              kf0[ks], qf[1][ks], sa[1][p * 2], 0, 0, 0);
          sa[0][p * 2 + 1] = __builtin_amdgcn_mfma_f32_32x32x16_bf16(
              kf1[ks], qf[0][ks], sa[0][p * 2 + 1], 0, 0, 0);
          sa[1][p * 2 + 1] = __builtin_amdgcn_mfma_f32_32x32x16_bf16(
              kf1[ks], qf[1][ks], sa[1][p * 2 + 1], 0, 0, 0);
        }
        __builtin_amdgcn_s_setprio(0);
      }

      // ---- causal mask + softmax, per strip
#pragma unroll
      for (int r = 0; r < 2; ++r) {
        const int sq0 = wq0 + r * 32;
        if (k0 + 127 > sq0) {
          int qq = sq0 + ql;
#pragma unroll
          for (int kt = 0; kt < 4; ++kt) {
            int kb = k0 + kt * 32 + 4 * h32;
#pragma unroll
            for (int rr = 0; rr < 16; ++rr) {
              int kk = kb + (rr & 3) + 8 * (rr >> 2);
              if (qq < kk) sa[r][kt][rr] = -1e9f;
            }
          }
        }

        float tmax = -1e30f;
#pragma unroll
        for (int kt = 0; kt < 4; ++kt)
#pragma unroll
          for (int rr = 0; rr < 16; ++rr) tmax = fmaxf(tmax, sa[r][kt][rr]);
        tmax = fmaxf(tmax, __shfl_xor(tmax, 32));

        if (!__all(tmax <= mrun[r] + 11.5f)) {
          float mnew = fmaxf(mrun[r], tmax);
          float e = __builtin_amdgcn_exp2f(mrun[r] - mnew);
          lrun[r] *= e;
          mrun[r] = mnew;
#pragma unroll
          for (int dt = 0; dt < 4; ++dt) o[r][dt] *= e;
        }

        float rsum = 0.f;
#pragma unroll
        for (int kt = 0; kt < 4; ++kt)
#pragma unroll
          for (int rr = 0; rr < 16; ++rr) {
            float p = __builtin_amdgcn_exp2f(sa[r][kt][rr] - mrun[r]);
            sa[r][kt][rr] = p;
            rsum += p;
          }
        rsum += __shfl_xor(rsum, 32);
        lrun[r] += rsum;
      }

      // ---- PV: vf read once per (kt,u2), used by BOTH strips
#pragma unroll
      for (int kt = 0; kt < 4; ++kt) {
#pragma unroll
        for (int u2 = 0; u2 < 2; ++u2) {
          int c = 4 * kt + 2 * u2 + h32;
          bf16x8 vf[4];
#pragma unroll
          for (int dt = 0; dt < 4; ++dt) {
            int row = dt * 32 + ql;
            vf[dt] = *(const bf16x8*)(Vc + row * 256 + ((c ^ swz0) << 4));
          }
#pragma unroll
          for (int r = 0; r < 2; ++r) {
            int A0, B0, A1, B1;
            asm("v_cvt_pk_bf16_f32 %0, %1, %2"
                : "=v"(A0) : "v"(sa[r][kt][u2 * 8 + 0]), "v"(sa[r][kt][u2 * 8 + 1]));
            asm("v_cvt_pk_bf16_f32 %0, %1, %2"
                : "=v"(B0) : "v"(sa[r][kt][u2 * 8 + 2]), "v"(sa[r][kt][u2 * 8 + 3]));
            asm("v_cvt_pk_bf16_f32 %0, %1, %2"
                : "=v"(A1) : "v"(sa[r][kt][u2 * 8 + 4]), "v"(sa[r][kt][u2 * 8 + 5]));
            asm("v_cvt_pk_bf16_f32 %0, %1, %2"
                : "=v"(B1) : "v"(sa[r][kt][u2 * 8 + 6]), "v"(sa[r][kt][u2 * 8 + 7]));
            auto r02 = __builtin_amdgcn_permlane32_swap(A0, A1, false, false);
            auto r13 = __builtin_amdgcn_permlane32_swap(B0, B1, false, false);
            union { int i[4]; bf16x8 v; } pu;
            pu.i[0] = r02[0];
            pu.i[1] = r13[0];
            pu.i[2] = r02[1];
            pu.i[3] = r13[1];
            __builtin_amdgcn_s_setprio(1);
#pragma unroll
            for (int dt = 0; dt < 4; ++dt)
              o[r][dt] = __builtin_amdgcn_mfma_f32_32x32x16_bf16(
                  vf[dt], pu.v, o[r][dt], 0, 0, 0);
            __builtin_amdgcn_s_setprio(0);
          }
        }
      }
    }
    asm volatile("s_waitcnt lgkmcnt(0)" ::: "memory");
    __builtin_amdgcn_s_barrier();
  }

  // ---- epilogue: both strips
  const int b = bh >> 4, h = bh & 15;
#pragma unroll
  for (int r = 0; r < 2; ++r) {
    float inv = 1.0f / lrun[r];
    size_t rowbase = ((size_t)b * 2048 + (wq0 + r * 32 + ql)) * 2048 + h * 128;
#pragma unroll
    for (int dt = 0; dt < 4; ++dt)
#pragma unroll
      for (int r4 = 0; r4 < 4; ++r4) {
        int col = dt * 32 + r4 * 8 + h32 * 4;
        ushort4 pk;
        pk.x = f2bf(o[r][dt][r4 * 4 + 0] * inv);
        pk.y = f2bf(o[r][dt][r4 * 4 + 1] * inv);
        pk.z = f2bf(o[r][dt][r4 * 4 + 2] * inv);
        pk.w = f2bf(o[r][dt][r4 * 4 + 3] * inv);
        *(ushort4*)(Og + rowbase + col) = pk;
      }
  }
}

// ---------------------------------------------------------------- launch
extern "C" void kernel_launch(void* const* d_in, const int* in_sizes, int n_in,
                              void* d_out, int out_size, void* d_ws,
                              size_t ws_size, hipStream_t stream) {
  const float* x = (const float*)d_in[0];
  const float* w_qkv = (const float*)d_in[1];
  const float* b_qkv = (const float*)d_in[2];
  const float* w_out = (const float*)d_in[3];
  const float* b_out = (const float*)d_in[4];
  float* out = (float*)d_out;
  char* ws = (char*)d_ws;

  if (ws_size < 92274688u) return;
  ushort* xb = (ushort*)(ws);
  ushort* wqkvt = (ushort*)(ws + 16777216);
  ushort* Q = (ushort*)(ws + 41943040);
  ushort* Kb = (ushort*)(ws + 58720256);
  ushort* Vt = (ushort*)(ws + 75497472);
  ushort* comb = xb;
  ushort* woutt = wqkvt;

  // fused: x cast (8192 blocks) + w_qkv transpose (3072 blocks)
  prep_kernel<<<dim3(11264), 256, 0, stream>>>((const float4*)x, (ushort4*)xb,
                                               w_qkv, wqkvt);
  gemm_bt_kernel<1><<<dim3(48, 32), 256, 0, stream>>>(
      xb, wqkvt, b_qkv, nullptr, Q, Kb, Vt, 4096, 6144, 2048);
  transpose_cast_kernel<<<dim3(32, 32), 256, 0, stream>>>(w_out, woutt, 2048,
                                                          2048);
  attn_kernel<<<dim3(256), 256, 0, stream>>>(Q, Kb, Vt, comb);
  gemm_bt_kernel<0><<<dim3(16, 32), 256, 0, stream>>>(
      comb, woutt, b_out, out, nullptr, nullptr, nullptr, 4096, 2048, 2048);
}

// Round 14
// 238.339 us; speedup vs baseline: 1.5462x; 1.5462x over previous
//
#include <hip/hip_runtime.h>
#include <hip/hip_bf16.h>

typedef __attribute__((ext_vector_type(4))) float f32x4;
typedef __attribute__((ext_vector_type(16))) float f32x16;
typedef __attribute__((ext_vector_type(8))) short bf16x8;

#define GBL_AS(p) (const __attribute__((address_space(1))) void*)(p)
#define LDS_AS(p) (__attribute__((address_space(3))) void*)(p)

__device__ __forceinline__ void gload_lds16(const void* g, void* l) {
  __builtin_amdgcn_global_load_lds(GBL_AS(g), LDS_AS(l), 16, 0, 0);
}

__device__ __forceinline__ ushort f2bf(float f) {
  union { float f; unsigned int u; } v; v.f = f;
  unsigned int r = v.u + 0x7fffu + ((v.u >> 16) & 1u);
  return (ushort)(r >> 16);
}

// ---------------------------------------------------------------- fused prep:
// blocks [0,8192): cast x f32->bf16; blocks [8192,11264): transpose w_qkv
__global__ void prep_kernel(const float4* __restrict__ x4,
                            ushort4* __restrict__ xb4,
                            const float* __restrict__ wqkv,
                            ushort* __restrict__ wqkvt) {
  __shared__ float tile[64][65];
  const int blk = blockIdx.x;
  if (blk < 8192) {
    int i = blk * 256 + threadIdx.x;
    float4 v = x4[i];
    ushort4 o;
    o.x = f2bf(v.x); o.y = f2bf(v.y); o.z = f2bf(v.z); o.w = f2bf(v.w);
    xb4[i] = o;
  } else {
    const int idx = blk - 8192;
    const int bx = idx % 96, by = idx / 96;
    const int C = 6144, R = 2048;
    int tx = threadIdx.x & 63, ty = threadIdx.x >> 6;
    int r0 = by * 64, c0 = bx * 64;
#pragma unroll
    for (int i = 0; i < 64; i += 4)
      tile[ty + i][tx] = wqkv[(size_t)(r0 + ty + i) * C + (c0 + tx)];
    __syncthreads();
#pragma unroll
    for (int i = 0; i < 64; i += 4)
      wqkvt[(size_t)(c0 + ty + i) * R + (r0 + tx)] = f2bf(tile[tx][ty + i]);
  }
}

// ------------------------------------------------- transpose + cast (w_out)
__global__ void transpose_cast_kernel(const float* __restrict__ in,
                                      ushort* __restrict__ out, int R, int C) {
  __shared__ float tile[64][65];
  int tx = threadIdx.x & 63, ty = threadIdx.x >> 6;
  int r0 = blockIdx.y * 64, c0 = blockIdx.x * 64;
#pragma unroll
  for (int i = 0; i < 64; i += 4)
    tile[ty + i][tx] = in[(size_t)(r0 + ty + i) * C + (c0 + tx)];
  __syncthreads();
#pragma unroll
  for (int i = 0; i < 64; i += 4)
    out[(size_t)(c0 + ty + i) * R + (r0 + tx)] = f2bf(tile[tx][ty + i]);
}

// ---------------------------------------------------------------- GEMM1 (QKV), 32x32x16 MFMA
// A: [M][K] bf16, Bt: [N][K] bf16. 128^2 tile, BK=64, 4 waves, wave tile
// 64x64 = acc[2][2] of 32x32 frags. Same staging/swizzle as 16x16 version.
// A-frag: row = l&31, k-slice (l>>5)*8; C/D: col=l&31,
// row=(reg&3)+8*(reg>>2)+4*(l>>5) — layouts verified by attn kernel.
// Scatter: Q*log2e/sqrt(128) -> [B*H][S][D]; K -> [B*H][S][D]; V^T -> [B*H][D][S].
__global__ __launch_bounds__(256, 2) void gemm32_qkv_kernel(
    const ushort* __restrict__ A, const ushort* __restrict__ Bt,
    const float* __restrict__ bias, ushort* __restrict__ Qo,
    ushort* __restrict__ Ko, ushort* __restrict__ Vo, int M, int N, int K) {
  __shared__ ushort As[128 * 64];
  __shared__ ushort Bs[128 * 64];
  const int tid = threadIdx.x;
  const int w = tid >> 6, l = tid & 63;
  const int wr = w >> 1, wc = w & 1;
  const int l31 = l & 31, h32 = l >> 5;
  const int m0 = blockIdx.y * 128, n0 = blockIdx.x * 128;

  f32x16 acc[2][2];
#pragma unroll
  for (int mi = 0; mi < 2; ++mi)
#pragma unroll
    for (int ni = 0; ni < 2; ++ni) acc[mi][ni] = 0.f;

  const int lr = l >> 3;             // staging row-in-1KB-group
  const int lc = (l & 7) ^ lr;       // pre-swizzled source chunk

  for (int k0 = 0; k0 < K; k0 += 64) {
#pragma unroll
    for (int i = 0; i < 4; ++i) {
      int row = i * 32 + w * 8 + lr;
      gload_lds16(A + (size_t)(m0 + row) * K + k0 + lc * 8,
                  (char*)As + (i * 32 + w * 8) * 128);
      gload_lds16(Bt + (size_t)(n0 + row) * K + k0 + lc * 8,
                  (char*)Bs + (i * 32 + w * 8) * 128);
    }
    __syncthreads();
    const char* Ab = (const char*)As;
    const char* Bb = (const char*)Bs;
    // 4 k-steps of 16, processed in 2 pairs: batch 8 frag reads then 8 MFMA
#pragma unroll
    for (int kp = 0; kp < 2; ++kp) {
      bf16x8 af[2][2], bf[2][2];
#pragma unroll
      for (int ks = 0; ks < 2; ++ks) {
        int c = (kp * 2 + ks) * 2 + h32;   // chunk = kstep*2 + (l>>5)
#pragma unroll
        for (int mi = 0; mi < 2; ++mi) {
          int row = wr * 64 + mi * 32 + l31;
          af[ks][mi] = *(const bf16x8*)(Ab + row * 128 + ((c ^ (row & 7)) << 4));
        }
#pragma unroll
        for (int ni = 0; ni < 2; ++ni) {
          int row = wc * 64 + ni * 32 + l31;
          bf[ks][ni] = *(const bf16x8*)(Bb + row * 128 + ((c ^ (row & 7)) << 4));
        }
      }
      __builtin_amdgcn_s_setprio(1);
#pragma unroll
      for (int ks = 0; ks < 2; ++ks)
#pragma unroll
        for (int mi = 0; mi < 2; ++mi)
#pragma unroll
          for (int ni = 0; ni < 2; ++ni)
            acc[mi][ni] = __builtin_amdgcn_mfma_f32_32x32x16_bf16(
                af[ks][mi], bf[ks][ni], acc[mi][ni], 0, 0, 0);
      __builtin_amdgcn_s_setprio(0);
    }
    __syncthreads();
  }

  // scatter epilogue; reg r -> m-offset (r&3) + 8*(r>>2) + 4*h32
  const float qscale = 0.08838834764831845f * 1.4426950408889634f;
#pragma unroll
  for (int ni = 0; ni < 2; ++ni) {
    int n = n0 + wc * 64 + ni * 32 + l31;
    int which = n >> 11;
    int cc2 = n & 2047;
    int h = cc2 >> 7, d = cc2 & 127;
    float b = bias[n];
#pragma unroll
    for (int mi = 0; mi < 2; ++mi) {
#pragma unroll
      for (int g4 = 0; g4 < 4; ++g4) {
        int m = m0 + wr * 64 + mi * 32 + g4 * 8 + 4 * h32;
        int bb = m >> 11, s = m & 2047;
        int bh = bb * 16 + h;
        if (which == 0) {
#pragma unroll
          for (int r = 0; r < 4; ++r)
            Qo[((size_t)bh * 2048 + s + r) * 128 + d] =
                f2bf((acc[mi][ni][g4 * 4 + r] + b) * qscale);
        } else if (which == 1) {
#pragma unroll
          for (int r = 0; r < 4; ++r)
            Ko[((size_t)bh * 2048 + s + r) * 128 + d] =
                f2bf(acc[mi][ni][g4 * 4 + r] + b);
        } else {
          ushort4 pk;
          pk.x = f2bf(acc[mi][ni][g4 * 4 + 0] + b);
          pk.y = f2bf(acc[mi][ni][g4 * 4 + 1] + b);
          pk.z = f2bf(acc[mi][ni][g4 * 4 + 2] + b);
          pk.w = f2bf(acc[mi][ni][g4 * 4 + 3] + b);
          *(ushort4*)(Vo + ((size_t)bh * 128 + d) * 2048 + s) = pk;
        }
      }
    }
  }
}

// ---------------------------------------------------------------- GEMM2 (16x16, proven)
__global__ __launch_bounds__(256, 2) void gemm_bt_kernel(
    const ushort* __restrict__ A, const ushort* __restrict__ Bt,
    const float* __restrict__ bias, float* __restrict__ C, int M, int N,
    int K) {
  __shared__ ushort As[128 * 64];
  __shared__ ushort Bs[128 * 64];
  const int tid = threadIdx.x;
  const int w = tid >> 6, l = tid & 63;
  const int wr = w >> 1, wc = w & 1;
  const int m0 = blockIdx.y * 128, n0 = blockIdx.x * 128;

  f32x4 acc[4][4] = {};

  const int lr = l >> 3;
  const int lc = (l & 7) ^ lr;

  for (int k0 = 0; k0 < K; k0 += 64) {
#pragma unroll
    for (int i = 0; i < 4; ++i) {
      int row = i * 32 + w * 8 + lr;
      gload_lds16(A + (size_t)(m0 + row) * K + k0 + lc * 8,
                  (char*)As + (i * 32 + w * 8) * 128);
      gload_lds16(Bt + (size_t)(n0 + row) * K + k0 + lc * 8,
                  (char*)Bs + (i * 32 + w * 8) * 128);
    }
    __syncthreads();
    const char* Ab = (const char*)As;
    const char* Bb = (const char*)Bs;
#pragma unroll
    for (int ks = 0; ks < 2; ++ks) {
      bf16x8 af[4], bfr[4];
      int cc = ks * 4 + (l >> 4);
#pragma unroll
      for (int mi = 0; mi < 4; ++mi) {
        int row = wr * 64 + mi * 16 + (l & 15);
        af[mi] = *(const bf16x8*)(Ab + row * 128 + ((cc ^ (row & 7)) << 4));
      }
#pragma unroll
      for (int ni = 0; ni < 4; ++ni) {
        int row = wc * 64 + ni * 16 + (l & 15);
        bfr[ni] = *(const bf16x8*)(Bb + row * 128 + ((cc ^ (row & 7)) << 4));
      }
#pragma unroll
      for (int mi = 0; mi < 4; ++mi)
#pragma unroll
        for (int ni = 0; ni < 4; ++ni)
          acc[mi][ni] = __builtin_amdgcn_mfma_f32_16x16x32_bf16(
              af[mi], bfr[ni], acc[mi][ni], 0, 0, 0);
    }
    __syncthreads();
  }

#pragma unroll
  for (int mi = 0; mi < 4; ++mi) {
    int row = m0 + wr * 64 + mi * 16 + ((l >> 4) << 2);
#pragma unroll
    for (int ni = 0; ni < 4; ++ni) {
      int col = n0 + wc * 64 + ni * 16 + (l & 15);
      float b = bias[col];
#pragma unroll
      for (int rr = 0; rr < 4; ++rr)
        C[(size_t)(row + rr) * N + col] = acc[mi][ni][rr] + b;
    }
  }
}

// ---------------------------------------------------------------- flash attention
// Round-12 proven version: swapped-QK^T, KVBLK=128, 8-wave paired blocks
// (heavy qb=8+j with light 7-j), K/V dbuf 128KB LDS, counted vmcnt,
// in-register softmax (exp2, defer-max), cvt_pk+permlane P->bf16.
__global__ __launch_bounds__(512, 2) void attn_kernel(
    const ushort* __restrict__ Qg, const ushort* __restrict__ Kg,
    const ushort* __restrict__ Vtg, ushort* __restrict__ Og) {
  constexpr int S = 2048, D = 128;
  __shared__ ushort Kl[2][128 * 128];
  __shared__ ushort Vl[2][128 * 128];

  const int tid = threadIdx.x, w = tid >> 6, l = tid & 63;
  const int lid = blockIdx.x;
  const int bh = lid & 31;
  const int j = lid >> 5;
  const int g = w >> 2, wv = w & 3;
  const int qb = (g == 0) ? (8 + j) : (7 - j);
  const int wq0 = qb * 128 + wv * 32;
  const int nt_blk = 9 + j;
  const int ql = l & 31, h32 = l >> 5;

  const ushort* Qb = Qg + (size_t)bh * S * D;
  const ushort* Kb = Kg + (size_t)bh * S * D;
  const ushort* Vb = Vtg + (size_t)bh * D * S;

  bf16x8 qf[8];
#pragma unroll
  for (int ks = 0; ks < 8; ++ks)
    qf[ks] = *(const bf16x8*)(Qb + (size_t)(wq0 + ql) * D + ks * 16 + h32 * 8);

  f32x16 o[4];
#pragma unroll
  for (int dt = 0; dt < 4; ++dt) o[dt] = 0.f;
  float mrun = -1e30f, lrun = 0.f;

  auto stage = [&](int t, int buf) {
    const int k0 = t * 128;
#pragma unroll
    for (int s2 = 0; s2 < 4; ++s2) {
      int i = w * 4 + s2;
      int row = i * 4 + (l >> 4);
      int ck = (l & 15) ^ (row & 7);
      gload_lds16(Kb + (size_t)(k0 + row) * D + ck * 8,
                  (char*)Kl[buf] + i * 1024);
    }
#pragma unroll
    for (int s2 = 0; s2 < 4; ++s2) {
      int i = w * 4 + s2;
      int row = i * 4 + (l >> 4);
      int ck = (l & 15) ^ (row & 7);
      gload_lds16(Vb + (size_t)row * S + k0 + ck * 8,
                  (char*)Vl[buf] + i * 1024);
    }
  };

  stage(0, 0);

  for (int t = 0; t < nt_blk; ++t) {
    const int cur = t & 1;
    const int k0 = t * 128;
    if (t + 1 < nt_blk) {
      stage(t + 1, cur ^ 1);
      asm volatile("s_waitcnt vmcnt(8)" ::: "memory");
    } else {
      asm volatile("s_waitcnt vmcnt(0)" ::: "memory");
    }
    __builtin_amdgcn_s_barrier();

    if (k0 < wq0 + 32) {
      const char* Kc = (const char*)Kl[cur];
      const char* Vc = (const char*)Vl[cur];
      const int swz0 = ql & 7;

      f32x16 sa[4];
#pragma unroll
      for (int kt = 0; kt < 4; ++kt) sa[kt] = 0.f;
#pragma unroll
      for (int p = 0; p < 2; ++p) {
        bf16x8 kf0[8], kf1[8];
        const char* base0 = Kc + (p * 64 + ql) * 256;
        const char* base1 = Kc + (p * 64 + 32 + ql) * 256;
#pragma unroll
        for (int ks = 0; ks < 8; ++ks) {
          int c = 2 * ks + h32;
          kf0[ks] = *(const bf16x8*)(base0 + ((c ^ swz0) << 4));
          kf1[ks] = *(const bf16x8*)(base1 + ((c ^ swz0) << 4));
        }
        __builtin_amdgcn_s_setprio(1);
#pragma unroll
        for (int ks = 0; ks < 8; ++ks) {
          sa[p * 2] = __builtin_amdgcn_mfma_f32_32x32x16_bf16(
              kf0[ks], qf[ks], sa[p * 2], 0, 0, 0);
          sa[p * 2 + 1] = __builtin_amdgcn_mfma_f32_32x32x16_bf16(
              kf1[ks], qf[ks], sa[p * 2 + 1], 0, 0, 0);
        }
        __builtin_amdgcn_s_setprio(0);
      }

      if (k0 + 127 > wq0) {
        int qq = wq0 + ql;
#pragma unroll
        for (int kt = 0; kt < 4; ++kt) {
          int kb = k0 + kt * 32 + 4 * h32;
#pragma unroll
          for (int rr = 0; rr < 16; ++rr) {
            int kk = kb + (rr & 3) + 8 * (rr >> 2);
            if (qq < kk) sa[kt][rr] = -1e9f;
          }
        }
      }

      float tmax = -1e30f;
#pragma unroll
      for (int kt = 0; kt < 4; ++kt)
#pragma unroll
        for (int rr = 0; rr < 16; ++rr) tmax = fmaxf(tmax, sa[kt][rr]);
      tmax = fmaxf(tmax, __shfl_xor(tmax, 32));

      if (!__all(tmax <= mrun + 11.5f)) {
        float mnew = fmaxf(mrun, tmax);
        float e = __builtin_amdgcn_exp2f(mrun - mnew);
        lrun *= e;
        mrun = mnew;
#pragma unroll
        for (int dt = 0; dt < 4; ++dt) o[dt] *= e;
      }

      float rsum = 0.f;
#pragma unroll
      for (int kt = 0; kt < 4; ++kt)
#pragma unroll
        for (int rr = 0; rr < 16; ++rr) {
          float p = __builtin_amdgcn_exp2f(sa[kt][rr] - mrun);
          sa[kt][rr] = p;
          rsum += p;
        }
      rsum += __shfl_xor(rsum, 32);
      lrun += rsum;

#pragma unroll
      for (int kt = 0; kt < 4; ++kt) {
#pragma unroll
        for (int u2 = 0; u2 < 2; ++u2) {
          int c = 4 * kt + 2 * u2 + h32;
          bf16x8 vf[4];
#pragma unroll
          for (int dt = 0; dt < 4; ++dt) {
            int row = dt * 32 + ql;
            vf[dt] = *(const bf16x8*)(Vc + row * 256 + ((c ^ swz0) << 4));
          }
          int A0, B0, A1, B1;
          asm("v_cvt_pk_bf16_f32 %0, %1, %2"
              : "=v"(A0) : "v"(sa[kt][u2 * 8 + 0]), "v"(sa[kt][u2 * 8 + 1]));
          asm("v_cvt_pk_bf16_f32 %0, %1, %2"
              : "=v"(B0) : "v"(sa[kt][u2 * 8 + 2]), "v"(sa[kt][u2 * 8 + 3]));
          asm("v_cvt_pk_bf16_f32 %0, %1, %2"
              : "=v"(A1) : "v"(sa[kt][u2 * 8 + 4]), "v"(sa[kt][u2 * 8 + 5]));
          asm("v_cvt_pk_bf16_f32 %0, %1, %2"
              : "=v"(B1) : "v"(sa[kt][u2 * 8 + 6]), "v"(sa[kt][u2 * 8 + 7]));
          auto r02 = __builtin_amdgcn_permlane32_swap(A0, A1, false, false);
          auto r13 = __builtin_amdgcn_permlane32_swap(B0, B1, false, false);
          union { int i[4]; bf16x8 v; } pu;
          pu.i[0] = r02[0];
          pu.i[1] = r13[0];
          pu.i[2] = r02[1];
          pu.i[3] = r13[1];
          __builtin_amdgcn_s_setprio(1);
#pragma unroll
          for (int dt = 0; dt < 4; ++dt)
            o[dt] = __builtin_amdgcn_mfma_f32_32x32x16_bf16(vf[dt], pu.v, o[dt],
                                                            0, 0, 0);
          __builtin_amdgcn_s_setprio(0);
        }
      }
    }
    asm volatile("s_waitcnt lgkmcnt(0)" ::: "memory");
    __builtin_amdgcn_s_barrier();
  }

  const int b = bh >> 4, h = bh & 15;
  float inv = 1.0f / lrun;
  size_t rowbase = ((size_t)b * 2048 + (wq0 + ql)) * 2048 + h * 128;
#pragma unroll
  for (int dt = 0; dt < 4; ++dt)
#pragma unroll
    for (int r4 = 0; r4 < 4; ++r4) {
      int col = dt * 32 + r4 * 8 + h32 * 4;
      ushort4 pk;
      pk.x = f2bf(o[dt][r4 * 4 + 0] * inv);
      pk.y = f2bf(o[dt][r4 * 4 + 1] * inv);
      pk.z = f2bf(o[dt][r4 * 4 + 2] * inv);
      pk.w = f2bf(o[dt][r4 * 4 + 3] * inv);
      *(ushort4*)(Og + rowbase + col) = pk;
    }
}

// ---------------------------------------------------------------- launch
extern "C" void kernel_launch(void* const* d_in, const int* in_sizes, int n_in,
                              void* d_out, int out_size, void* d_ws,
                              size_t ws_size, hipStream_t stream) {
  const float* x = (const float*)d_in[0];
  const float* w_qkv = (const float*)d_in[1];
  const float* b_qkv = (const float*)d_in[2];
  const float* w_out = (const float*)d_in[3];
  const float* b_out = (const float*)d_in[4];
  float* out = (float*)d_out;
  char* ws = (char*)d_ws;

  if (ws_size < 92274688u) return;
  ushort* xb = (ushort*)(ws);
  ushort* wqkvt = (ushort*)(ws + 16777216);
  ushort* Q = (ushort*)(ws + 41943040);
  ushort* Kb = (ushort*)(ws + 58720256);
  ushort* Vt = (ushort*)(ws + 75497472);
  ushort* comb = xb;
  ushort* woutt = wqkvt;

  // fused: x cast (8192 blocks) + w_qkv transpose (3072 blocks)
  prep_kernel<<<dim3(11264), 256, 0, stream>>>((const float4*)x, (ushort4*)xb,
                                               w_qkv, wqkvt);
  gemm32_qkv_kernel<<<dim3(48, 32), 256, 0, stream>>>(
      xb, wqkvt, b_qkv, Q, Kb, Vt, 4096, 6144, 2048);
  transpose_cast_kernel<<<dim3(32, 32), 256, 0, stream>>>(w_out, woutt, 2048,
                                                          2048);
  attn_kernel<<<dim3(256), 512, 0, stream>>>(Q, Kb, Vt, comb);
  gemm_bt_kernel<<<dim3(16, 32), 256, 0, stream>>>(comb, woutt, b_out, out,
                                                   4096, 2048, 2048);
}

// Round 15
// 221.576 us; speedup vs baseline: 1.6632x; 1.0757x over previous
//
#include <hip/hip_runtime.h>
#include <hip/hip_bf16.h>

typedef __attribute__((ext_vector_type(4))) float f32x4;
typedef __attribute__((ext_vector_type(16))) float f32x16;
typedef __attribute__((ext_vector_type(8))) short bf16x8;

#define GBL_AS(p) (const __attribute__((address_space(1))) void*)(p)
#define LDS_AS(p) (__attribute__((address_space(3))) void*)(p)

__device__ __forceinline__ void gload_lds16(const void* g, void* l) {
  __builtin_amdgcn_global_load_lds(GBL_AS(g), LDS_AS(l), 16, 0, 0);
}

__device__ __forceinline__ ushort f2bf(float f) {
  union { float f; unsigned int u; } v; v.f = f;
  unsigned int r = v.u + 0x7fffu + ((v.u >> 16) & 1u);
  return (ushort)(r >> 16);
}

// ---------------------------------------------------------------- fused prep:
// blocks [0,8192): cast x f32->bf16 (float4/ushort4 chunks)
// blocks [8192,11264): transpose+cast w_qkv [2048][6144] -> [6144][2048] bf16
__global__ void prep_kernel(const float4* __restrict__ x4,
                            ushort4* __restrict__ xb4,
                            const float* __restrict__ wqkv,
                            ushort* __restrict__ wqkvt) {
  __shared__ float tile[64][65];
  const int blk = blockIdx.x;
  if (blk < 8192) {
    int i = blk * 256 + threadIdx.x;
    float4 v = x4[i];
    ushort4 o;
    o.x = f2bf(v.x); o.y = f2bf(v.y); o.z = f2bf(v.z); o.w = f2bf(v.w);
    xb4[i] = o;
  } else {
    const int idx = blk - 8192;
    const int bx = idx % 96, by = idx / 96;   // 96 x 32 tiles
    const int C = 6144, R = 2048;
    int tx = threadIdx.x & 63, ty = threadIdx.x >> 6;
    int r0 = by * 64, c0 = bx * 64;
#pragma unroll
    for (int i = 0; i < 64; i += 4)
      tile[ty + i][tx] = wqkv[(size_t)(r0 + ty + i) * C + (c0 + tx)];
    __syncthreads();
#pragma unroll
    for (int i = 0; i < 64; i += 4)
      wqkvt[(size_t)(c0 + ty + i) * R + (r0 + tx)] = f2bf(tile[tx][ty + i]);
  }
}

// ------------------------------------------------- transpose + cast: [R][C]f32 -> [C][R]bf16
__global__ void transpose_cast_kernel(const float* __restrict__ in,
                                      ushort* __restrict__ out, int R, int C) {
  __shared__ float tile[64][65];
  int tx = threadIdx.x & 63, ty = threadIdx.x >> 6;
  int r0 = blockIdx.y * 64, c0 = blockIdx.x * 64;
#pragma unroll
  for (int i = 0; i < 64; i += 4)
    tile[ty + i][tx] = in[(size_t)(r0 + ty + i) * C + (c0 + tx)];
  __syncthreads();
#pragma unroll
  for (int i = 0; i < 64; i += 4)
    out[(size_t)(c0 + ty + i) * R + (r0 + tx)] = f2bf(tile[tx][ty + i]);
}

// ---------------------------------------------------------------- bf16 GEMM, Bt layout
// A: [M][K] bf16, Bt: [N][K] bf16.  MODE 0: C=f32 [M][N] + bias.
// MODE 1: QKV scatter: Q scaled by log2(e)/sqrt(128) -> [B*H][S][D];
//         K -> [B*H][S][D]; V -> transposed [B*H][D][S].
template <int MODE>
__global__ __launch_bounds__(256, 2) void gemm_bt_kernel(
    const ushort* __restrict__ A, const ushort* __restrict__ Bt,
    const float* __restrict__ bias, float* __restrict__ C,
    ushort* __restrict__ Qo, ushort* __restrict__ Ko, ushort* __restrict__ Vo,
    int M, int N, int K) {
  __shared__ ushort As[128 * 64];
  __shared__ ushort Bs[128 * 64];
  const int tid = threadIdx.x;
  const int w = tid >> 6, l = tid & 63;
  const int wr = w >> 1, wc = w & 1;
  const int m0 = blockIdx.y * 128, n0 = blockIdx.x * 128;

  f32x4 acc[4][4] = {};

  const int lr = l >> 3;             // row-in-1KB-group (0..7)
  const int lc = (l & 7) ^ lr;       // pre-swizzled source chunk

  for (int k0 = 0; k0 < K; k0 += 64) {
#pragma unroll
    for (int i = 0; i < 4; ++i) {
      int row = i * 32 + w * 8 + lr;
      gload_lds16(A + (size_t)(m0 + row) * K + k0 + lc * 8,
                  (char*)As + (i * 32 + w * 8) * 128);
      gload_lds16(Bt + (size_t)(n0 + row) * K + k0 + lc * 8,
                  (char*)Bs + (i * 32 + w * 8) * 128);
    }
    __syncthreads();
    const char* Ab = (const char*)As;
    const char* Bb = (const char*)Bs;
#pragma unroll
    for (int ks = 0; ks < 2; ++ks) {
      bf16x8 af[4], bfr[4];
      int cc = ks * 4 + (l >> 4);
#pragma unroll
      for (int mi = 0; mi < 4; ++mi) {
        int row = wr * 64 + mi * 16 + (l & 15);
        af[mi] = *(const bf16x8*)(Ab + row * 128 + ((cc ^ (row & 7)) << 4));
      }
#pragma unroll
      for (int ni = 0; ni < 4; ++ni) {
        int row = wc * 64 + ni * 16 + (l & 15);
        bfr[ni] = *(const bf16x8*)(Bb + row * 128 + ((cc ^ (row & 7)) << 4));
      }
#pragma unroll
      for (int mi = 0; mi < 4; ++mi)
#pragma unroll
        for (int ni = 0; ni < 4; ++ni)
          acc[mi][ni] = __builtin_amdgcn_mfma_f32_16x16x32_bf16(
              af[mi], bfr[ni], acc[mi][ni], 0, 0, 0);
    }
    __syncthreads();
  }

  if (MODE == 0) {
#pragma unroll
    for (int mi = 0; mi < 4; ++mi) {
      int row = m0 + wr * 64 + mi * 16 + ((l >> 4) << 2);
#pragma unroll
      for (int ni = 0; ni < 4; ++ni) {
        int col = n0 + wc * 64 + ni * 16 + (l & 15);
        float b = bias[col];
#pragma unroll
        for (int r = 0; r < 4; ++r)
          C[(size_t)(row + r) * N + col] = acc[mi][ni][r] + b;
      }
    }
  } else {
    // log2(e)/sqrt(128): softmax runs in exp2 domain
    const float qscale = 0.08838834764831845f * 1.4426950408889634f;
#pragma unroll
    for (int ni = 0; ni < 4; ++ni) {
      int n = n0 + wc * 64 + ni * 16 + (l & 15);
      int which = n >> 11;
      int cc2 = n & 2047;
      int h = cc2 >> 7, d = cc2 & 127;
      float b = bias[n];
#pragma unroll
      for (int mi = 0; mi < 4; ++mi) {
        int m = m0 + wr * 64 + mi * 16 + ((l >> 4) << 2);
        int bb = m >> 11, s = m & 2047;
        int bh = bb * 16 + h;
        if (which == 0) {
#pragma unroll
          for (int r = 0; r < 4; ++r)
            Qo[((size_t)bh * 2048 + s + r) * 128 + d] =
                f2bf((acc[mi][ni][r] + b) * qscale);
        } else if (which == 1) {
#pragma unroll
          for (int r = 0; r < 4; ++r)
            Ko[((size_t)bh * 2048 + s + r) * 128 + d] = f2bf(acc[mi][ni][r] + b);
        } else {
          ushort4 pk;
          pk.x = f2bf(acc[mi][ni][0] + b);
          pk.y = f2bf(acc[mi][ni][1] + b);
          pk.z = f2bf(acc[mi][ni][2] + b);
          pk.w = f2bf(acc[mi][ni][3] + b);
          *(ushort4*)(Vo + ((size_t)bh * 128 + d) * 2048 + s) = pk;
        }
      }
    }
  }
}

// ---------------------------------------------------------------- flash attention
// Round-12 proven version: swapped-QK^T, KVBLK=128, 8-wave paired blocks
// (heavy qb=8+j with light 7-j), K/V dbuf 128KB LDS, counted vmcnt,
// in-register softmax (exp2, defer-max), cvt_pk+permlane P->bf16.
__global__ __launch_bounds__(512, 2) void attn_kernel(
    const ushort* __restrict__ Qg, const ushort* __restrict__ Kg,
    const ushort* __restrict__ Vtg, ushort* __restrict__ Og) {
  constexpr int S = 2048, D = 128;
  __shared__ ushort Kl[2][128 * 128];
  __shared__ ushort Vl[2][128 * 128];

  const int tid = threadIdx.x, w = tid >> 6, l = tid & 63;
  const int lid = blockIdx.x;
  const int bh = lid & 31;
  const int j = lid >> 5;
  const int g = w >> 2, wv = w & 3;
  const int qb = (g == 0) ? (8 + j) : (7 - j);
  const int wq0 = qb * 128 + wv * 32;
  const int nt_blk = 9 + j;
  const int ql = l & 31, h32 = l >> 5;

  const ushort* Qb = Qg + (size_t)bh * S * D;
  const ushort* Kb = Kg + (size_t)bh * S * D;
  const ushort* Vb = Vtg + (size_t)bh * D * S;

  bf16x8 qf[8];
#pragma unroll
  for (int ks = 0; ks < 8; ++ks)
    qf[ks] = *(const bf16x8*)(Qb + (size_t)(wq0 + ql) * D + ks * 16 + h32 * 8);

  f32x16 o[4];
#pragma unroll
  for (int dt = 0; dt < 4; ++dt) o[dt] = 0.f;
  float mrun = -1e30f, lrun = 0.f;

  auto stage = [&](int t, int buf) {
    const int k0 = t * 128;
#pragma unroll
    for (int s2 = 0; s2 < 4; ++s2) {
      int i = w * 4 + s2;
      int row = i * 4 + (l >> 4);
      int ck = (l & 15) ^ (row & 7);
      gload_lds16(Kb + (size_t)(k0 + row) * D + ck * 8,
                  (char*)Kl[buf] + i * 1024);
    }
#pragma unroll
    for (int s2 = 0; s2 < 4; ++s2) {
      int i = w * 4 + s2;
      int row = i * 4 + (l >> 4);
      int ck = (l & 15) ^ (row & 7);
      gload_lds16(Vb + (size_t)row * S + k0 + ck * 8,
                  (char*)Vl[buf] + i * 1024);
    }
  };

  stage(0, 0);

  for (int t = 0; t < nt_blk; ++t) {
    const int cur = t & 1;
    const int k0 = t * 128;
    if (t + 1 < nt_blk) {
      stage(t + 1, cur ^ 1);
      asm volatile("s_waitcnt vmcnt(8)" ::: "memory");
    } else {
      asm volatile("s_waitcnt vmcnt(0)" ::: "memory");
    }
    __builtin_amdgcn_s_barrier();

    if (k0 < wq0 + 32) {
      const char* Kc = (const char*)Kl[cur];
      const char* Vc = (const char*)Vl[cur];
      const int swz0 = ql & 7;

      f32x16 sa[4];
#pragma unroll
      for (int kt = 0; kt < 4; ++kt) sa[kt] = 0.f;
#pragma unroll
      for (int p = 0; p < 2; ++p) {
        bf16x8 kf0[8], kf1[8];
        const char* base0 = Kc + (p * 64 + ql) * 256;
        const char* base1 = Kc + (p * 64 + 32 + ql) * 256;
#pragma unroll
        for (int ks = 0; ks < 8; ++ks) {
          int c = 2 * ks + h32;
          kf0[ks] = *(const bf16x8*)(base0 + ((c ^ swz0) << 4));
          kf1[ks] = *(const bf16x8*)(base1 + ((c ^ swz0) << 4));
        }
        __builtin_amdgcn_s_setprio(1);
#pragma unroll
        for (int ks = 0; ks < 8; ++ks) {
          sa[p * 2] = __builtin_amdgcn_mfma_f32_32x32x16_bf16(
              kf0[ks], qf[ks], sa[p * 2], 0, 0, 0);
          sa[p * 2 + 1] = __builtin_amdgcn_mfma_f32_32x32x16_bf16(
              kf1[ks], qf[ks], sa[p * 2 + 1], 0, 0, 0);
        }
        __builtin_amdgcn_s_setprio(0);
      }

      if (k0 + 127 > wq0) {
        int qq = wq0 + ql;
#pragma unroll
        for (int kt = 0; kt < 4; ++kt) {
          int kb = k0 + kt * 32 + 4 * h32;
#pragma unroll
          for (int rr = 0; rr < 16; ++rr) {
            int kk = kb + (rr & 3) + 8 * (rr >> 2);
            if (qq < kk) sa[kt][rr] = -1e9f;
          }
        }
      }

      float tmax = -1e30f;
#pragma unroll
      for (int kt = 0; kt < 4; ++kt)
#pragma unroll
        for (int rr = 0; rr < 16; ++rr) tmax = fmaxf(tmax, sa[kt][rr]);
      tmax = fmaxf(tmax, __shfl_xor(tmax, 32));

      if (!__all(tmax <= mrun + 11.5f)) {
        float mnew = fmaxf(mrun, tmax);
        float e = __builtin_amdgcn_exp2f(mrun - mnew);
        lrun *= e;
        mrun = mnew;
#pragma unroll
        for (int dt = 0; dt < 4; ++dt) o[dt] *= e;
      }

      float rsum = 0.f;
#pragma unroll
      for (int kt = 0; kt < 4; ++kt)
#pragma unroll
        for (int rr = 0; rr < 16; ++rr) {
          float p = __builtin_amdgcn_exp2f(sa[kt][rr] - mrun);
          sa[kt][rr] = p;
          rsum += p;
        }
      rsum += __shfl_xor(rsum, 32);
      lrun += rsum;

#pragma unroll
      for (int kt = 0; kt < 4; ++kt) {
#pragma unroll
        for (int u2 = 0; u2 < 2; ++u2) {
          int c = 4 * kt + 2 * u2 + h32;
          bf16x8 vf[4];
#pragma unroll
          for (int dt = 0; dt < 4; ++dt) {
            int row = dt * 32 + ql;
            vf[dt] = *(const bf16x8*)(Vc + row * 256 + ((c ^ swz0) << 4));
          }
          int A0, B0, A1, B1;
          asm("v_cvt_pk_bf16_f32 %0, %1, %2"
              : "=v"(A0) : "v"(sa[kt][u2 * 8 + 0]), "v"(sa[kt][u2 * 8 + 1]));
          asm("v_cvt_pk_bf16_f32 %0, %1, %2"
              : "=v"(B0) : "v"(sa[kt][u2 * 8 + 2]), "v"(sa[kt][u2 * 8 + 3]));
          asm("v_cvt_pk_bf16_f32 %0, %1, %2"
              : "=v"(A1) : "v"(sa[kt][u2 * 8 + 4]), "v"(sa[kt][u2 * 8 + 5]));
          asm("v_cvt_pk_bf16_f32 %0, %1, %2"
              : "=v"(B1) : "v"(sa[kt][u2 * 8 + 6]), "v"(sa[kt][u2 * 8 + 7]));
          auto r02 = __builtin_amdgcn_permlane32_swap(A0, A1, false, false);
          auto r13 = __builtin_amdgcn_permlane32_swap(B0, B1, false, false);
          union { int i[4]; bf16x8 v; } pu;
          pu.i[0] = r02[0];
          pu.i[1] = r13[0];
          pu.i[2] = r02[1];
          pu.i[3] = r13[1];
          __builtin_amdgcn_s_setprio(1);
#pragma unroll
          for (int dt = 0; dt < 4; ++dt)
            o[dt] = __builtin_amdgcn_mfma_f32_32x32x16_bf16(vf[dt], pu.v, o[dt],
                                                            0, 0, 0);
          __builtin_amdgcn_s_setprio(0);
        }
      }
    }
    asm volatile("s_waitcnt lgkmcnt(0)" ::: "memory");
    __builtin_amdgcn_s_barrier();
  }

  const int b = bh >> 4, h = bh & 15;
  float inv = 1.0f / lrun;
  size_t rowbase = ((size_t)b * 2048 + (wq0 + ql)) * 2048 + h * 128;
#pragma unroll
  for (int dt = 0; dt < 4; ++dt)
#pragma unroll
    for (int r4 = 0; r4 < 4; ++r4) {
      int col = dt * 32 + r4 * 8 + h32 * 4;
      ushort4 pk;
      pk.x = f2bf(o[dt][r4 * 4 + 0] * inv);
      pk.y = f2bf(o[dt][r4 * 4 + 1] * inv);
      pk.z = f2bf(o[dt][r4 * 4 + 2] * inv);
      pk.w = f2bf(o[dt][r4 * 4 + 3] * inv);
      *(ushort4*)(Og + rowbase + col) = pk;
    }
}

// ---------------------------------------------------------------- launch
extern "C" void kernel_launch(void* const* d_in, const int* in_sizes, int n_in,
                              void* d_out, int out_size, void* d_ws,
                              size_t ws_size, hipStream_t stream) {
  const float* x = (const float*)d_in[0];
  const float* w_qkv = (const float*)d_in[1];
  const float* b_qkv = (const float*)d_in[2];
  const float* w_out = (const float*)d_in[3];
  const float* b_out = (const float*)d_in[4];
  float* out = (float*)d_out;
  char* ws = (char*)d_ws;

  if (ws_size < 92274688u) return;
  ushort* xb = (ushort*)(ws);
  ushort* wqkvt = (ushort*)(ws + 16777216);
  ushort* Q = (ushort*)(ws + 41943040);
  ushort* Kb = (ushort*)(ws + 58720256);
  ushort* Vt = (ushort*)(ws + 75497472);
  ushort* comb = xb;
  ushort* woutt = wqkvt;

  // fused: x cast (8192 blocks) + w_qkv transpose (3072 blocks)
  prep_kernel<<<dim3(11264), 256, 0, stream>>>((const float4*)x, (ushort4*)xb,
                                               w_qkv, wqkvt);
  gemm_bt_kernel<1><<<dim3(48, 32), 256, 0, stream>>>(
      xb, wqkvt, b_qkv, nullptr, Q, Kb, Vt, 4096, 6144, 2048);
  transpose_cast_kernel<<<dim3(32, 32), 256, 0, stream>>>(w_out, woutt, 2048,
                                                          2048);
  attn_kernel<<<dim3(256), 512, 0, stream>>>(Q, Kb, Vt, comb);
  gemm_bt_kernel<0><<<dim3(16, 32), 256, 0, stream>>>(
      comb, woutt, b_out, out, nullptr, nullptr, nullptr, 4096, 2048, 2048);
}

// Round 16
// 215.549 us; speedup vs baseline: 1.7097x; 1.0280x over previous
//
#include <hip/hip_runtime.h>
#include <hip/hip_bf16.h>

typedef __attribute__((ext_vector_type(4))) float f32x4;
typedef __attribute__((ext_vector_type(16))) float f32x16;
typedef __attribute__((ext_vector_type(8))) short bf16x8;

#define GBL_AS(p) (const __attribute__((address_space(1))) void*)(p)
#define LDS_AS(p) (__attribute__((address_space(3))) void*)(p)

__device__ __forceinline__ void gload_lds16(const void* g, void* l) {
  __builtin_amdgcn_global_load_lds(GBL_AS(g), LDS_AS(l), 16, 0, 0);
}

__device__ __forceinline__ ushort f2bf(float f) {
  union { float f; unsigned int u; } v; v.f = f;
  unsigned int r = v.u + 0x7fffu + ((v.u >> 16) & 1u);
  return (ushort)(r >> 16);
}

// ---------------------------------------------------------------- fused prep:
// blocks [0,8192): cast x f32->bf16 (float4/ushort4 chunks)
// blocks [8192,11264): transpose+cast w_qkv [2048][6144] -> [6144][2048] bf16
__global__ void prep_kernel(const float4* __restrict__ x4,
                            ushort4* __restrict__ xb4,
                            const float* __restrict__ wqkv,
                            ushort* __restrict__ wqkvt) {
  __shared__ float tile[64][65];
  const int blk = blockIdx.x;
  if (blk < 8192) {
    int i = blk * 256 + threadIdx.x;
    float4 v = x4[i];
    ushort4 o;
    o.x = f2bf(v.x); o.y = f2bf(v.y); o.z = f2bf(v.z); o.w = f2bf(v.w);
    xb4[i] = o;
  } else {
    const int idx = blk - 8192;
    const int bx = idx % 96, by = idx / 96;   // 96 x 32 tiles
    const int C = 6144, R = 2048;
    int tx = threadIdx.x & 63, ty = threadIdx.x >> 6;
    int r0 = by * 64, c0 = bx * 64;
#pragma unroll
    for (int i = 0; i < 64; i += 4)
      tile[ty + i][tx] = wqkv[(size_t)(r0 + ty + i) * C + (c0 + tx)];
    __syncthreads();
#pragma unroll
    for (int i = 0; i < 64; i += 4)
      wqkvt[(size_t)(c0 + ty + i) * R + (r0 + tx)] = f2bf(tile[tx][ty + i]);
  }
}

// ---------------------------------------------------------------- bf16 GEMM, Bt layout
// A: [M][K] bf16, Bt: [N][K] bf16.  MODE 0: C=f32 [M][N] + bias.
// MODE 1: QKV scatter: Q scaled by log2(e)/sqrt(128) -> [B*H][S][D];
//         K -> [B*H][S][D]; V -> transposed [B*H][D][S].
template <int MODE>
__global__ __launch_bounds__(256, 2) void gemm_bt_kernel(
    const ushort* __restrict__ A, const ushort* __restrict__ Bt,
    const float* __restrict__ bias, float* __restrict__ C,
    ushort* __restrict__ Qo, ushort* __restrict__ Ko, ushort* __restrict__ Vo,
    int M, int N, int K) {
  __shared__ ushort As[128 * 64];
  __shared__ ushort Bs[128 * 64];
  const int tid = threadIdx.x;
  const int w = tid >> 6, l = tid & 63;
  const int wr = w >> 1, wc = w & 1;
  const int m0 = blockIdx.y * 128, n0 = blockIdx.x * 128;

  f32x4 acc[4][4] = {};

  const int lr = l >> 3;             // row-in-1KB-group (0..7)
  const int lc = (l & 7) ^ lr;       // pre-swizzled source chunk

  for (int k0 = 0; k0 < K; k0 += 64) {
#pragma unroll
    for (int i = 0; i < 4; ++i) {
      int row = i * 32 + w * 8 + lr;
      gload_lds16(A + (size_t)(m0 + row) * K + k0 + lc * 8,
                  (char*)As + (i * 32 + w * 8) * 128);
      gload_lds16(Bt + (size_t)(n0 + row) * K + k0 + lc * 8,
                  (char*)Bs + (i * 32 + w * 8) * 128);
    }
    __syncthreads();
    const char* Ab = (const char*)As;
    const char* Bb = (const char*)Bs;
#pragma unroll
    for (int ks = 0; ks < 2; ++ks) {
      bf16x8 af[4], bfr[4];
      int cc = ks * 4 + (l >> 4);
#pragma unroll
      for (int mi = 0; mi < 4; ++mi) {
        int row = wr * 64 + mi * 16 + (l & 15);
        af[mi] = *(const bf16x8*)(Ab + row * 128 + ((cc ^ (row & 7)) << 4));
      }
#pragma unroll
      for (int ni = 0; ni < 4; ++ni) {
        int row = wc * 64 + ni * 16 + (l & 15);
        bfr[ni] = *(const bf16x8*)(Bb + row * 128 + ((cc ^ (row & 7)) << 4));
      }
#pragma unroll
      for (int mi = 0; mi < 4; ++mi)
#pragma unroll
        for (int ni = 0; ni < 4; ++ni)
          acc[mi][ni] = __builtin_amdgcn_mfma_f32_16x16x32_bf16(
              af[mi], bfr[ni], acc[mi][ni], 0, 0, 0);
    }
    __syncthreads();
  }

  if (MODE == 0) {
#pragma unroll
    for (int mi = 0; mi < 4; ++mi) {
      int row = m0 + wr * 64 + mi * 16 + ((l >> 4) << 2);
#pragma unroll
      for (int ni = 0; ni < 4; ++ni) {
        int col = n0 + wc * 64 + ni * 16 + (l & 15);
        float b = bias[col];
#pragma unroll
        for (int r = 0; r < 4; ++r)
          C[(size_t)(row + r) * N + col] = acc[mi][ni][r] + b;
      }
    }
  } else {
    // log2(e)/sqrt(128): softmax runs in exp2 domain
    const float qscale = 0.08838834764831845f * 1.4426950408889634f;
#pragma unroll
    for (int ni = 0; ni < 4; ++ni) {
      int n = n0 + wc * 64 + ni * 16 + (l & 15);
      int which = n >> 11;
      int cc2 = n & 2047;
      int h = cc2 >> 7, d = cc2 & 127;
      float b = bias[n];
#pragma unroll
      for (int mi = 0; mi < 4; ++mi) {
        int m = m0 + wr * 64 + mi * 16 + ((l >> 4) << 2);
        int bb = m >> 11, s = m & 2047;
        int bh = bb * 16 + h;
        if (which == 0) {
#pragma unroll
          for (int r = 0; r < 4; ++r)
            Qo[((size_t)bh * 2048 + s + r) * 128 + d] =
                f2bf((acc[mi][ni][r] + b) * qscale);
        } else if (which == 1) {
#pragma unroll
          for (int r = 0; r < 4; ++r)
            Ko[((size_t)bh * 2048 + s + r) * 128 + d] = f2bf(acc[mi][ni][r] + b);
        } else {
          ushort4 pk;
          pk.x = f2bf(acc[mi][ni][0] + b);
          pk.y = f2bf(acc[mi][ni][1] + b);
          pk.z = f2bf(acc[mi][ni][2] + b);
          pk.w = f2bf(acc[mi][ni][3] + b);
          *(ushort4*)(Vo + ((size_t)bh * 128 + d) * 2048 + s) = pk;
        }
      }
    }
  }
}

// ---------------------------------------------------------------- flash attention + w_out^T backfill
// blocks [0,256): round-12 proven attn — swapped-QK^T, KVBLK=128, 8-wave
// paired blocks (heavy qb=8+j with light 7-j), K/V dbuf 128KB LDS, counted
// vmcnt, in-register softmax (exp2, defer-max), cvt_pk+permlane P->bf16.
// blocks [256,1280): w_out [2048][2048] f32 -> transposed bf16 (backfills
// the attn idle tail: attn block durations vary 9..16 tiles, 1 block/CU).
__global__ __launch_bounds__(512, 2) void attn_kernel(
    const ushort* __restrict__ Qg, const ushort* __restrict__ Kg,
    const ushort* __restrict__ Vtg, ushort* __restrict__ Og,
    const float* __restrict__ wout, ushort* __restrict__ woutt) {
  constexpr int S = 2048, D = 128;
  __shared__ ushort Kl[2][128 * 128];
  __shared__ ushort Vl[2][128 * 128];

  const int tid = threadIdx.x;

  if (blockIdx.x >= 256) {
    // ---- w_out transpose backfill: 1024 blocks of 64x64 tiles
    float* tile = (float*)&Kl[0][0];             // 64 x 65 f32 = 16.6KB
    const int idx = blockIdx.x - 256;
    const int bx = idx & 31, by = idx >> 5;
    const int r0 = by * 64, c0 = bx * 64;
    const int tx = tid & 63, ty = tid >> 6;      // ty: 0..7
#pragma unroll
    for (int i = 0; i < 64; i += 8)
      tile[(ty + i) * 65 + tx] = wout[(size_t)(r0 + ty + i) * 2048 + c0 + tx];
    __syncthreads();
#pragma unroll
    for (int i = 0; i < 64; i += 8)
      woutt[(size_t)(c0 + ty + i) * 2048 + r0 + tx] =
          f2bf(tile[tx * 65 + ty + i]);
    return;
  }

  const int w = tid >> 6, l = tid & 63;
  const int lid = blockIdx.x;
  const int bh = lid & 31;
  const int j = lid >> 5;
  const int g = w >> 2, wv = w & 3;
  const int qb = (g == 0) ? (8 + j) : (7 - j);
  const int wq0 = qb * 128 + wv * 32;
  const int nt_blk = 9 + j;
  const int ql = l & 31, h32 = l >> 5;

  const ushort* Qb = Qg + (size_t)bh * S * D;
  const ushort* Kb = Kg + (size_t)bh * S * D;
  const ushort* Vb = Vtg + (size_t)bh * D * S;

  bf16x8 qf[8];
#pragma unroll
  for (int ks = 0; ks < 8; ++ks)
    qf[ks] = *(const bf16x8*)(Qb + (size_t)(wq0 + ql) * D + ks * 16 + h32 * 8);

  f32x16 o[4];
#pragma unroll
  for (int dt = 0; dt < 4; ++dt) o[dt] = 0.f;
  float mrun = -1e30f, lrun = 0.f;

  auto stage = [&](int t, int buf) {
    const int k0 = t * 128;
#pragma unroll
    for (int s2 = 0; s2 < 4; ++s2) {
      int i = w * 4 + s2;
      int row = i * 4 + (l >> 4);
      int ck = (l & 15) ^ (row & 7);
      gload_lds16(Kb + (size_t)(k0 + row) * D + ck * 8,
                  (char*)Kl[buf] + i * 1024);
    }
#pragma unroll
    for (int s2 = 0; s2 < 4; ++s2) {
      int i = w * 4 + s2;
      int row = i * 4 + (l >> 4);
      int ck = (l & 15) ^ (row & 7);
      gload_lds16(Vb + (size_t)row * S + k0 + ck * 8,
                  (char*)Vl[buf] + i * 1024);
    }
  };

  stage(0, 0);

  for (int t = 0; t < nt_blk; ++t) {
    const int cur = t & 1;
    const int k0 = t * 128;
    if (t + 1 < nt_blk) {
      stage(t + 1, cur ^ 1);
      asm volatile("s_waitcnt vmcnt(8)" ::: "memory");
    } else {
      asm volatile("s_waitcnt vmcnt(0)" ::: "memory");
    }
    __builtin_amdgcn_s_barrier();

    if (k0 < wq0 + 32) {
      const char* Kc = (const char*)Kl[cur];
      const char* Vc = (const char*)Vl[cur];
      const int swz0 = ql & 7;

      f32x16 sa[4];
#pragma unroll
      for (int kt = 0; kt < 4; ++kt) sa[kt] = 0.f;
#pragma unroll
      for (int p = 0; p < 2; ++p) {
        bf16x8 kf0[8], kf1[8];
        const char* base0 = Kc + (p * 64 + ql) * 256;
        const char* base1 = Kc + (p * 64 + 32 + ql) * 256;
#pragma unroll
        for (int ks = 0; ks < 8; ++ks) {
          int c = 2 * ks + h32;
          kf0[ks] = *(const bf16x8*)(base0 + ((c ^ swz0) << 4));
          kf1[ks] = *(const bf16x8*)(base1 + ((c ^ swz0) << 4));
        }
        __builtin_amdgcn_s_setprio(1);
#pragma unroll
        for (int ks = 0; ks < 8; ++ks) {
          sa[p * 2] = __builtin_amdgcn_mfma_f32_32x32x16_bf16(
              kf0[ks], qf[ks], sa[p * 2], 0, 0, 0);
          sa[p * 2 + 1] = __builtin_amdgcn_mfma_f32_32x32x16_bf16(
              kf1[ks], qf[ks], sa[p * 2 + 1], 0, 0, 0);
        }
        __builtin_amdgcn_s_setprio(0);
      }

      if (k0 + 127 > wq0) {
        int qq = wq0 + ql;
#pragma unroll
        for (int kt = 0; kt < 4; ++kt) {
          int kb = k0 + kt * 32 + 4 * h32;
#pragma unroll
          for (int rr = 0; rr < 16; ++rr) {
            int kk = kb + (rr & 3) + 8 * (rr >> 2);
            if (qq < kk) sa[kt][rr] = -1e9f;
          }
        }
      }

      float tmax = -1e30f;
#pragma unroll
      for (int kt = 0; kt < 4; ++kt)
#pragma unroll
        for (int rr = 0; rr < 16; ++rr) tmax = fmaxf(tmax, sa[kt][rr]);
      tmax = fmaxf(tmax, __shfl_xor(tmax, 32));

      if (!__all(tmax <= mrun + 11.5f)) {
        float mnew = fmaxf(mrun, tmax);
        float e = __builtin_amdgcn_exp2f(mrun - mnew);
        lrun *= e;
        mrun = mnew;
#pragma unroll
        for (int dt = 0; dt < 4; ++dt) o[dt] *= e;
      }

      float rsum = 0.f;
#pragma unroll
      for (int kt = 0; kt < 4; ++kt)
#pragma unroll
        for (int rr = 0; rr < 16; ++rr) {
          float p = __builtin_amdgcn_exp2f(sa[kt][rr] - mrun);
          sa[kt][rr] = p;
          rsum += p;
        }
      rsum += __shfl_xor(rsum, 32);
      lrun += rsum;

#pragma unroll
      for (int kt = 0; kt < 4; ++kt) {
#pragma unroll
        for (int u2 = 0; u2 < 2; ++u2) {
          int c = 4 * kt + 2 * u2 + h32;
          bf16x8 vf[4];
#pragma unroll
          for (int dt = 0; dt < 4; ++dt) {
            int row = dt * 32 + ql;
            vf[dt] = *(const bf16x8*)(Vc + row * 256 + ((c ^ swz0) << 4));
          }
          int A0, B0, A1, B1;
          asm("v_cvt_pk_bf16_f32 %0, %1, %2"
              : "=v"(A0) : "v"(sa[kt][u2 * 8 + 0]), "v"(sa[kt][u2 * 8 + 1]));
          asm("v_cvt_pk_bf16_f32 %0, %1, %2"
              : "=v"(B0) : "v"(sa[kt][u2 * 8 + 2]), "v"(sa[kt][u2 * 8 + 3]));
          asm("v_cvt_pk_bf16_f32 %0, %1, %2"
              : "=v"(A1) : "v"(sa[kt][u2 * 8 + 4]), "v"(sa[kt][u2 * 8 + 5]));
          asm("v_cvt_pk_bf16_f32 %0, %1, %2"
              : "=v"(B1) : "v"(sa[kt][u2 * 8 + 6]), "v"(sa[kt][u2 * 8 + 7]));
          auto r02 = __builtin_amdgcn_permlane32_swap(A0, A1, false, false);
          auto r13 = __builtin_amdgcn_permlane32_swap(B0, B1, false, false);
          union { int i[4]; bf16x8 v; } pu;
          pu.i[0] = r02[0];
          pu.i[1] = r13[0];
          pu.i[2] = r02[1];
          pu.i[3] = r13[1];
          __builtin_amdgcn_s_setprio(1);
#pragma unroll
          for (int dt = 0; dt < 4; ++dt)
            o[dt] = __builtin_amdgcn_mfma_f32_32x32x16_bf16(vf[dt], pu.v, o[dt],
                                                            0, 0, 0);
          __builtin_amdgcn_s_setprio(0);
        }
      }
    }
    asm volatile("s_waitcnt lgkmcnt(0)" ::: "memory");
    __builtin_amdgcn_s_barrier();
  }

  const int b = bh >> 4, h = bh & 15;
  float inv = 1.0f / lrun;
  size_t rowbase = ((size_t)b * 2048 + (wq0 + ql)) * 2048 + h * 128;
#pragma unroll
  for (int dt = 0; dt < 4; ++dt)
#pragma unroll
    for (int r4 = 0; r4 < 4; ++r4) {
      int col = dt * 32 + r4 * 8 + h32 * 4;
      ushort4 pk;
      pk.x = f2bf(o[dt][r4 * 4 + 0] * inv);
      pk.y = f2bf(o[dt][r4 * 4 + 1] * inv);
      pk.z = f2bf(o[dt][r4 * 4 + 2] * inv);
      pk.w = f2bf(o[dt][r4 * 4 + 3] * inv);
      *(ushort4*)(Og + rowbase + col) = pk;
    }
}

// ---------------------------------------------------------------- launch
extern "C" void kernel_launch(void* const* d_in, const int* in_sizes, int n_in,
                              void* d_out, int out_size, void* d_ws,
                              size_t ws_size, hipStream_t stream) {
  const float* x = (const float*)d_in[0];
  const float* w_qkv = (const float*)d_in[1];
  const float* b_qkv = (const float*)d_in[2];
  const float* w_out = (const float*)d_in[3];
  const float* b_out = (const float*)d_in[4];
  float* out = (float*)d_out;
  char* ws = (char*)d_ws;

  if (ws_size < 92274688u) return;
  ushort* xb = (ushort*)(ws);
  ushort* wqkvt = (ushort*)(ws + 16777216);
  ushort* Q = (ushort*)(ws + 41943040);
  ushort* Kb = (ushort*)(ws + 58720256);
  ushort* Vt = (ushort*)(ws + 75497472);
  ushort* comb = xb;
  ushort* woutt = wqkvt;   // aliases w_qkv^T region (dead after GEMM1)

  // fused: x cast (8192 blocks) + w_qkv transpose (3072 blocks)
  prep_kernel<<<dim3(11264), 256, 0, stream>>>((const float4*)x, (ushort4*)xb,
                                               w_qkv, wqkvt);
  gemm_bt_kernel<1><<<dim3(48, 32), 256, 0, stream>>>(
      xb, wqkvt, b_qkv, nullptr, Q, Kb, Vt, 4096, 6144, 2048);
  // attn (blocks 0..255) + w_out transpose backfill (blocks 256..1279)
  attn_kernel<<<dim3(1280), 512, 0, stream>>>(Q, Kb, Vt, comb, w_out, woutt);
  gemm_bt_kernel<0><<<dim3(16, 32), 256, 0, stream>>>(
      comb, woutt, b_out, out, nullptr, nullptr, nullptr, 4096, 2048, 2048);
}